// Round 6
// baseline (322.170 us; speedup 1.0000x reference)
//
#include <hip/hip_runtime.h>

// iRPE contextual/transposed PRODUCT:
//   lt[b,h,i,k] = sum_d x[b,h,i,d] * W[h,d,k]   (K=49 GEMV per row)
//   out[b,h,i,j] = lt[b,h,i, bucket[i,j]]        (the 256 MB write)
//
// Round-6: DRAM-row-locality retest, unconfounded. Block = 4 consecutive i
// x 8 bh planes (LDS 14.1 KB, same as r5; grid 2048; NT stores). gid map
// gives a CU's 8 resident blocks 8 CONSECUTIVE igrps with the same bhg ->
// per plane the CU streams a 128-KB contiguous window in lockstep (vs 4-KB
// pieces at 4-MB stride in r5). Bucket read per-t from L1/L2 (linear,
// wave-shared) to keep VGPRs <= 64 for 8 blocks/CU.

constexpr int cL = 1024;
constexpr int cD = 64;
constexpr int cK = 49;
constexpr int IG = 4;             // consecutive i rows per block
constexpr int BG = 8;             // bh planes per block
constexpr int ROWS = IG * BG;     // 32

typedef float vf4 __attribute__((ext_vector_type(4)));

__global__ __launch_bounds__(256, 8) void irpe_fused(
    const float* __restrict__ x,       // (B,H,L,D) = (bh, i, d)
    const float* __restrict__ W,       // (H,D,K)
    const int*   __restrict__ bucket,  // (L,L), values in [0,49)
    float*       __restrict__ out)     // (B,H,L,L)
{
    __shared__ float xs[ROWS][cD];     // 8 KB
    __shared__ float lts[ROWS * cK];   // 6.125 KB

    // gid -> (igrp, bhg): CU c (round-robin, gid mod 256) receives gids
    // c+256k, k=0..7 -> igrp = (c&31)*8 + k (8 consecutive), bhg = c>>5
    // (fixed). Perf heuristic only; correctness is mapping-independent.
    const int gid  = blockIdx.x;
    const int k8   = gid >> 8;               // 0..7
    const int c    = gid & 255;
    const int igrp = ((c & 31) << 3) + k8;   // 0..255
    const int bhg  = c >> 5;                 // 0..7
    const int i0   = igrp * IG;
    const int bh0  = bhg * BG;
    const int tid  = threadIdx.x;
    const int lane = tid & 63;
    const int w    = tid >> 6;

    // ---- Phase A: stage 32 x rows (256 B each, coalesced float4) ----
    const vf4* x4 = (const vf4*)x;
    #pragma unroll
    for (int r = 0; r < 2; ++r) {
        const int idx = r * 256 + tid;
        const int row = idx >> 4;            // 0..31 = lhb*4 + li
        const int d4  = idx & 15;
        const int lhb = row >> 2;
        const int li  = row & 3;
        ((vf4*)xs[row])[d4] = __builtin_nontemporal_load(
            &x4[((size_t)(bh0 + lhb) * cL + (i0 + li)) * (cD / 4) + d4]);
    }
    __syncthreads();

    // ---- Phase B: lts[row*49+k] = sum_d xs[row][d] * W[h,d,k] ----
    // h = lhb since BG==8 and bh0 % 8 == 0. Lanes -> consecutive k =>
    // coalesced W loads (W is 100 KB, L2-resident).
    for (int p = tid; p < ROWS * cK; p += 256) {
        const int row = p / cK;
        const int k   = p - row * cK;
        const int h   = row >> 2;
        const float* wp = W + (size_t)h * cD * cK + k;
        const float* xr = xs[row];
        float acc = 0.0f;
        #pragma unroll 8
        for (int d = 0; d < cD; ++d)
            acc = fmaf(xr[d], wp[d * cK], acc);
        lts[p] = acc;
    }
    __syncthreads();

    // ---- Phase C: wave w streams planes lhb = 2w, 2w+1 ----
    // Per plane: 16 KB contiguous ascending walk (t = li*4 + jc).
    // Bucket int4 index i0*256 + t*64 + lane is ALSO linear in t; all 4
    // waves read the same 16 KB -> L1-hot after first touch.
    const int4* bpt = (const int4*)bucket + (size_t)i0 * (cL / 4);
    vf4* p0 = (vf4*)out + ((size_t)(bh0 + 2 * w    ) * cL + i0) * (cL / 4);
    vf4* p1 = (vf4*)out + ((size_t)(bh0 + 2 * w + 1) * cL + i0) * (cL / 4);
    const float* l0 = lts + (2 * w    ) * (IG * cK);
    const float* l1 = lts + (2 * w + 1) * (IG * cK);
    #pragma unroll 4
    for (int t = 0; t < 16; ++t) {
        const int li = t >> 2;
        const int4 bk = bpt[t * 64 + lane];
        const float* r0 = l0 + li * cK;
        const float* r1 = l1 + li * cK;
        vf4 o0, o1;
        o0.x = r0[bk.x]; o0.y = r0[bk.y]; o0.z = r0[bk.z]; o0.w = r0[bk.w];
        o1.x = r1[bk.x]; o1.y = r1[bk.y]; o1.z = r1[bk.z]; o1.w = r1[bk.w];
        __builtin_nontemporal_store(o0, &p0[t * 64 + lane]);
        __builtin_nontemporal_store(o1, &p1[t * 64 + lane]);
    }
}

extern "C" void kernel_launch(void* const* d_in, const int* in_sizes, int n_in,
                              void* d_out, int out_size, void* d_ws, size_t ws_size,
                              hipStream_t stream) {
    const float* x      = (const float*)d_in[0];   // (8,8,1024,64) fp32
    const float* W      = (const float*)d_in[1];   // (8,64,49) fp32
    const int*   bucket = (const int*)d_in[2];     // (1024,1024) int32
    float*       out    = (float*)d_out;           // (8,8,1024,1024) fp32

    const int grid = (cL / IG) * (64 / BG);        // 256 * 8 = 2048 blocks
    irpe_fused<<<grid, 256, 0, stream>>>(x, W, bucket, out);
}